// Round 6
// baseline (6854.864 us; speedup 1.0000x reference)
//
#include <hip/hip_runtime.h>
#include <math.h>

#define W_WIN 5
#define NSUB 2
#define MAX_SEG 64
#define MAX_T 256

__device__ __forceinline__ float softplusf(float v) {
    // jax.nn.softplus == logaddexp(v, 0) == max(v,0) + log1p(exp(-|v|))
    return fmaxf(v, 0.0f) + log1pf(expf(-fabsf(v)));
}

// ---------------- wave-level numpy-faithful reductions ----------------
__device__ __forceinline__ float npsum128(float e0, float e1) {
    int lane = threadIdx.x & 63;
    int k = lane & 7;
    float r = __shfl(e0, k, 64);
    #pragma unroll
    for (int m = 1; m < 8; ++m) r += __shfl(e0, k + 8 * m, 64);
    #pragma unroll
    for (int m = 0; m < 8; ++m) r += __shfl(e1, k + 8 * m, 64);
    float r0 = __shfl(r, 0, 64), r1 = __shfl(r, 1, 64), r2 = __shfl(r, 2, 64), r3 = __shfl(r, 3, 64);
    float r4 = __shfl(r, 4, 64), r5 = __shfl(r, 5, 64), r6 = __shfl(r, 6, 64), r7 = __shfl(r, 7, 64);
    return ((r0 + r1) + (r2 + r3)) + ((r4 + r5) + (r6 + r7));
}

__device__ __forceinline__ float wmax128(float e0, float e1) {
    float m = fmaxf(e0, e1);
    #pragma unroll
    for (int s = 1; s < 64; s <<= 1) m = fmaxf(m, __shfl_xor(m, s, 64));
    return m;
}

// ---------------- kernel 1: encoder (also writes traj_t output block) ----------------
__global__ void encode_kernel(const float* __restrict__ emb, const int* __restrict__ hi,
                              const float* __restrict__ w1, const float* __restrict__ b1,
                              const float* __restrict__ w2, const float* __restrict__ b2,
                              float* __restrict__ enc, float* __restrict__ out,
                              int B, int L, int D) {
    __shared__ float x[128];
    __shared__ float h[128];
    int row = blockIdx.x;           // 0 .. B*L-1
    int j = threadIdx.x;            // 0 .. D-1
    int idx = hi[row];
    x[j] = emb[(size_t)idx * D + j];
    __syncthreads();
    float s = b1[j];
    #pragma unroll 8
    for (int i = 0; i < 128; ++i) s += x[i] * w1[i * 128 + j];
    h[j] = fmaxf(s, 0.0f);
    __syncthreads();
    float o = b2[j];
    #pragma unroll 8
    for (int i = 0; i < 128; ++i) o += h[i] * w2[i * 128 + j];
    enc[(size_t)row * D + j] = o;
    int b = row / L, l = row % L;
    size_t OS = 2 + 2 * (size_t)L * D;
    out[(size_t)b * OS + 2 + (size_t)L * D + (size_t)l * D + j] = o;
}

// ---------------- kernel 1b: all window JSDs in parallel (1 wave / position) ----------------
__global__ __launch_bounds__(64) void jsd_kernel(
        const float* __restrict__ enc_all, const int* __restrict__ hl,
        float* __restrict__ jsdv, int L, int D) {
    const int b = blockIdx.x >> 7;
    const int j = blockIdx.x & 127;
    const int n = hl[b];
    if (n < 2 * W_WIN || j > n - 2 * W_WIN) return;
    const int lane = threadIdx.x;
    const float* r = enc_all + ((size_t)b * L + j) * D;
    float ml0 = ((((r[lane]       + r[128 + lane]) + r[256 + lane]) + r[384 + lane]) + r[512 + lane]) / 5.0f;
    float ml1 = ((((r[64 + lane]  + r[192 + lane]) + r[320 + lane]) + r[448 + lane]) + r[576 + lane]) / 5.0f;
    float mr0 = ((((r[640 + lane] + r[768 + lane]) + r[896 + lane]) + r[1024 + lane]) + r[1152 + lane]) / 5.0f;
    float mr1 = ((((r[704 + lane] + r[832 + lane]) + r[960 + lane]) + r[1088 + lane]) + r[1216 + lane]) / 5.0f;
    float mxl = wmax128(ml0, ml1), mxr = wmax128(mr0, mr1);
    float a0 = expf(ml0 - mxl), a1 = expf(ml1 - mxl);
    float c0 = expf(mr0 - mxr), c1 = expf(mr1 - mxr);
    float sl = npsum128(a0, a1), sr = npsum128(c0, c1);
    float p0 = a0 / sl + 1e-8f, p1 = a1 / sl + 1e-8f;
    float q0 = c0 / sr + 1e-8f, q1 = c1 / sr + 1e-8f;
    float sp = npsum128(p0, p1), sq = npsum128(q0, q1);
    p0 /= sp; p1 /= sp; q0 /= sq; q1 /= sq;
    float mv0 = 0.5f * (p0 + q0), mv1 = 0.5f * (p1 + q1);
    float t10 = p0 * logf(p0 / mv0), t11 = p1 * logf(p1 / mv1);
    float t20 = q0 * logf(q0 / mv0), t21 = q1 * logf(q1 / mv1);
    float s1 = npsum128(t10, t11), s2 = npsum128(t20, t21);
    if (lane == 0) jsdv[b * L + j] = 0.5f * s1 + 0.5f * s2;
}

// ---------------- kernel 2: plan building from precomputed JSDs (1 wave / batch) ----------------
__global__ __launch_bounds__(64) void plan_kernel(
        const float* __restrict__ enc_all, const float* __restrict__ ht,
        const int* __restrict__ hl, const float* __restrict__ pt,
        const float* __restrict__ jsdv,
        float* __restrict__ envs, float* __restrict__ dt_sched,
        int* __restrict__ envid, int* __restrict__ stateidx,
        int* __restrict__ Tcnt, int B, int L, int D) {
    const int b = blockIdx.x;
    const int lane = threadIdx.x;   // 0..63
    const float* encg = enc_all + (size_t)b * L * D;
    const float* times = ht + (size_t)b * L;

    __shared__ float encs[128 * 128];
    __shared__ double cand[160];
    __shared__ double bounds[40];
    __shared__ int starts[40];
    __shared__ int seg_s[40], seg_e[40];
    __shared__ int m_sh;

    for (int v = lane; v < 128 * 128 / 4; v += 64)
        ((float4*)encs)[v] = ((const float4*)encg)[v];
    int n = hl[b];
    __syncthreads();

    int nb = 1, ns = 1;             // uniform across the wave
    if (lane == 0) { bounds[0] = (double)times[0]; starts[0] = 0; }
    __syncthreads();

    if (n >= 2 * W_WIN) {
        int j = 0;
        while (j <= n - 2 * W_WIN) {
            float jsd = jsdv[b * L + j];        // uniform broadcast load
            if (jsd > 0.5f) {
                if (nb < 39 && ns < 39) {
                    if (lane == 0) {
                        bounds[nb] = ((double)times[j + W_WIN - 1] + (double)times[j + W_WIN]) * 0.5;
                        starts[ns] = j + W_WIN;
                    }
                    nb++; ns++;
                }
                j += W_WIN;
            } else {
                j += 1;
            }
        }
    }
    __syncthreads();

    {
        double lastb = bounds[nb - 1];
        if ((double)times[n - 1] > lastb) {
            if (lane == 0) bounds[nb] = (double)times[n - 1];
            nb++;
        }
    }
    if (lane == 0) {
        for (int si = 0; si < ns; ++si) {
            seg_s[si] = starts[si];
            seg_e[si] = (si + 1 < ns) ? (starts[si + 1] - 1) : (n - 1);
        }
    }
    __syncthreads();

    int C = 0;
    for (int si = 0; si < ns; ++si) {
        int s = seg_s[si], e = seg_e[si];
        if (lane == 0) {
            double t0 = bounds[si];
            double t1 = (si + 1 < nb) ? bounds[si + 1] : bounds[nb - 1];
            int m = 0;
            cand[m++] = t0;
            for (int l = s; l <= e; ++l) {
                double tv = (double)times[l];
                if (tv < t0 || tv > t1) continue;
                if (tv != cand[m - 1]) cand[m++] = tv;
            }
            if (t1 > cand[m - 1]) cand[m++] = t1;
            for (int k = 1; k < m; ++k)
                if (cand[k] - cand[k - 1] < 1e-6) cand[k] = cand[k - 1] + 1e-6;
            m_sh = m;
        }
        __syncthreads();
        int m = m_sh;
        int K = m - 1;
        if (C + K > MAX_T) K = MAX_T - C;
        for (int k = lane; k < K; k += 64) {
            dt_sched[b * MAX_T + C + k] = (float)(cand[k + 1] - cand[k]);
            envid[b * MAX_T + C + k] = si;
        }
        for (int l = s + lane; l <= e; l += 64) {
            double tv = (double)times[l];
            int best = 0;
            double bd = fabs(cand[0] - tv);
            for (int k = 1; k < m; ++k) {
                double dk = fabs(cand[k] - tv);
                if (dk < bd) { bd = dk; best = k; }
            }
            stateidx[b * L + l] = C + best;
        }
        __syncthreads();
        C += K;
    }

    if (lane == 0) {
        double ptv = (double)pt[b];
        if (ptv > bounds[nb - 1] + 1e-6 && C < MAX_T) {
            double a0d = bounds[nb - 1], a1d = ptv;
            if (a1d - a0d < 1e-6) a1d = a0d + 1e-6;
            dt_sched[b * MAX_T + C] = (float)(a1d - a0d);
            envid[b * MAX_T + C] = ns - 1;
            C++;
        }
        Tcnt[b] = C;
    }
    for (int si = 0; si < ns; ++si) {
        int s = seg_s[si], e = seg_e[si];
        float s0 = 0.0f, s1 = 0.0f;
        for (int l = s; l <= e; ++l) {
            s0 += encs[l * 128 + lane];
            s1 += encs[l * 128 + lane + 64];
        }
        float inv = 1.0f / (float)(e - s + 1);
        envs[((size_t)b * MAX_SEG + si) * 128 + lane] = s0 * inv;
        envs[((size_t)b * MAX_SEG + si) * 128 + lane + 64] = s1 * inv;
    }
}

// ---------------- kernel 3: SINGLE-WORKGROUP ODE — zero cross-WG communication ----
// grid = B blocks x 1024 thr; one block per batch, all weights in ONE CU's
// register file. The cross-WG rendezvous (2x ~2µs memory-side round trips per
// substep, the dominant term R0-R5) is replaced by __syncthreads (~100cy).
//
// Register budget (the R1/R5 spill lesson, fixed structurally + by attribute):
//   w1z[64] + w2r[256] + w3r[64] = 384 weight floats/thread (+ ~40 live) < 450
//   (m08 no-spill line). W1's env-half is NOT stored: env is segment-constant,
//   so its contribution c1 is a per-thread scalar recomputed from L2 on
//   segment change (proven in R5). amdgpu_waves_per_eu(4,4) pins the
//   allocator at 4 waves/EU (one 16-wave block/CU) -> 512-VGPR budget,
//   overriding the heuristic that capped R1/R5 at 128.
//
// Work split (1024 threads):
//   L1: h1 col = tid>>1, half h = tid&1 owns 64 z-rows   -> shfl_xor(1) combine
//   L2: h2 col = tid>>1, half h owns 256 h1-rows          -> shfl_xor(1) combine
//   L3: dz col = tid>>3, oct  o = tid&7 owns 64 h2-rows   -> shfl tree (1,2,4)
// LDS reads: xs/h1s are 2-address broadcasts (free); h2s is stored [8][68]
// (pad 68: quad = (o+k4)&7) so the o*64 stride is bank-visible -> spread.
__global__
__attribute__((amdgpu_flat_work_group_size(1024, 1024), amdgpu_waves_per_eu(4, 4)))
void ode_solo(
    const float* __restrict__ usert, const int* __restrict__ u,
    const float* __restrict__ vw1, const float* __restrict__ vb1,
    const float* __restrict__ vw2, const float* __restrict__ vb2,
    const float* __restrict__ vw3, const float* __restrict__ vb3,
    const float* __restrict__ emb, const int* __restrict__ pos, const int* __restrict__ neg,
    const float* __restrict__ envs, const float* __restrict__ dtsch,
    const int* __restrict__ envid, const int* __restrict__ stidx,
    const int* __restrict__ Tc,
    float* __restrict__ out, int B)
{
    const int batch = blockIdx.x;
    const int tid = threadIdx.x;            // 0..1023
    const int col2 = tid >> 1, h = tid & 1; // L1/L2 mapping
    const int cz = tid >> 3, o = tid & 7;   // L3 mapping

    __shared__ float xs[256];               // [z | env]
    __shared__ float h1s[512];
    __shared__ float h2s[8 * 68];           // [o-block][64 + 4 pad]
    __shared__ int sidx_sh[128];
    __shared__ float dts_sh[MAX_T];
    __shared__ int sid_sh[MAX_T];

    // ---- one-time weight staging into registers (static indices, full unroll) ----
    float w1z[64];                          // W1[h*64+k][col2], z-rows only
    #pragma unroll
    for (int k = 0; k < 64; ++k)
        w1z[k] = vw1[(size_t)(h * 64 + k) * 512 + col2];
    float w2r[256];                         // W2[h*256+k][col2]
    #pragma unroll
    for (int k = 0; k < 256; ++k)
        w2r[k] = vw2[(size_t)(h * 256 + k) * 512 + col2];
    float w3r[64];                          // W3[o*64+k][cz]
    #pragma unroll
    for (int k = 0; k < 64; ++k)
        w3r[k] = vw3[(size_t)(o * 64 + k) * 128 + cz];

    const float b1c = vb1[col2];
    const float b2c = vb2[col2];
    const float b3c = vb3[cz];

    if (tid < 128) sidx_sh[tid] = stidx[batch * 128 + tid];
    if (tid < MAX_T) {
        dts_sh[tid] = dtsch[batch * MAX_T + tid];
        sid_sh[tid] = envid[batch * MAX_T + tid];
    }

    const int T = Tc[batch];
    const size_t OS = 2 + 2 * (size_t)128 * 128;
    float* outb = out + (size_t)batch * OS;

    if (tid < 128) xs[tid] = usert[(size_t)u[batch] * 128 + tid];
    __syncthreads();

    // m=0 records
    int lp = 0;
    while (lp < 128 && sidx_sh[lp] == 0) {
        if (tid < 128) outb[2 + (size_t)lp * 128 + tid] = xs[tid];
        ++lp;
    }

    float c1 = 0.0f;                        // env-half of this thread's L1 partial
    int prev_si = -1;
    for (int t = 0; t < T; ++t) {
        const int si = sid_sh[t];
        const float hdt = dts_sh[t] * 0.5f; // dt / NSUB
        if (si != prev_si) {
            prev_si = si;
            const float* envp = envs + ((size_t)batch * MAX_SEG + si) * 128;
            if (tid >= 128 && tid < 256) xs[tid] = envp[tid - 128];
            __syncthreads();
            // c1 = W1env[h*64..+64][col2] . env  (2x32-serial + add, from L2)
            float e0 = 0.0f, e1 = 0.0f;
            #pragma unroll
            for (int k4 = 0; k4 < 8; ++k4) {
                float4 xv = *(const float4*)(xs + 128 + h * 64 + k4 * 4);
                e0 += vw1[(size_t)(128 + h * 64 + k4 * 4 + 0) * 512 + col2] * xv.x
                    + vw1[(size_t)(128 + h * 64 + k4 * 4 + 1) * 512 + col2] * xv.y
                    + vw1[(size_t)(128 + h * 64 + k4 * 4 + 2) * 512 + col2] * xv.z
                    + vw1[(size_t)(128 + h * 64 + k4 * 4 + 3) * 512 + col2] * xv.w;
            }
            #pragma unroll
            for (int k4 = 8; k4 < 16; ++k4) {
                float4 xv = *(const float4*)(xs + 128 + h * 64 + k4 * 4);
                e1 += vw1[(size_t)(128 + h * 64 + k4 * 4 + 0) * 512 + col2] * xv.x
                    + vw1[(size_t)(128 + h * 64 + k4 * 4 + 1) * 512 + col2] * xv.y
                    + vw1[(size_t)(128 + h * 64 + k4 * 4 + 2) * 512 + col2] * xv.z
                    + vw1[(size_t)(128 + h * 64 + k4 * 4 + 3) * 512 + col2] * xv.w;
            }
            c1 = e0 + e1;
        }
        #pragma unroll
        for (int sub = 0; sub < NSUB; ++sub) {
            // ---- layer 1: half-column partial (2x32-serial) + pair combine ----
            float a0 = 0.0f, a1 = 0.0f;
            #pragma unroll
            for (int k4 = 0; k4 < 8; ++k4) {
                float4 xv = *(const float4*)(xs + h * 64 + k4 * 4);
                a0 += w1z[k4 * 4 + 0] * xv.x + w1z[k4 * 4 + 1] * xv.y
                    + w1z[k4 * 4 + 2] * xv.z + w1z[k4 * 4 + 3] * xv.w;
            }
            #pragma unroll
            for (int k4 = 8; k4 < 16; ++k4) {
                float4 xv = *(const float4*)(xs + h * 64 + k4 * 4);
                a1 += w1z[k4 * 4 + 0] * xv.x + w1z[k4 * 4 + 1] * xv.y
                    + w1z[k4 * 4 + 2] * xv.z + w1z[k4 * 4 + 3] * xv.w;
            }
            float pz = (a0 + a1) + c1;
            float hsum = pz + __shfl_xor(pz, 1, 64);
            if (h == 0) h1s[col2] = softplusf(hsum + b1c);
            __syncthreads();
            // ---- layer 2: half-column partial (8x32-serial, tree) + pair combine ----
            float tacc[8] = {0, 0, 0, 0, 0, 0, 0, 0};
            const float* h1b = h1s + h * 256;
            #pragma unroll
            for (int j = 0; j < 8; ++j) {
                #pragma unroll
                for (int k4 = 0; k4 < 8; ++k4) {
                    float4 hv = *(const float4*)(h1b + j * 32 + k4 * 4);
                    tacc[j] += w2r[j * 32 + k4 * 4 + 0] * hv.x + w2r[j * 32 + k4 * 4 + 1] * hv.y
                             + w2r[j * 32 + k4 * 4 + 2] * hv.z + w2r[j * 32 + k4 * 4 + 3] * hv.w;
                }
            }
            float p2s = ((tacc[0] + tacc[1]) + (tacc[2] + tacc[3]))
                      + ((tacc[4] + tacc[5]) + (tacc[6] + tacc[7]));
            float h2sum = p2s + __shfl_xor(p2s, 1, 64);
            if (h == 0) h2s[(col2 >> 6) * 68 + (col2 & 63)] = softplusf(h2sum + b2c);
            __syncthreads();
            // ---- layer 3: oct partial (2x32-serial) + 8-way shfl tree ----
            float d0 = 0.0f, d1 = 0.0f;
            #pragma unroll
            for (int k4 = 0; k4 < 8; ++k4) {
                float4 hv = *(const float4*)(h2s + o * 68 + k4 * 4);
                d0 += w3r[k4 * 4 + 0] * hv.x + w3r[k4 * 4 + 1] * hv.y
                    + w3r[k4 * 4 + 2] * hv.z + w3r[k4 * 4 + 3] * hv.w;
            }
            #pragma unroll
            for (int k4 = 8; k4 < 16; ++k4) {
                float4 hv = *(const float4*)(h2s + o * 68 + k4 * 4);
                d1 += w3r[k4 * 4 + 0] * hv.x + w3r[k4 * 4 + 1] * hv.y
                    + w3r[k4 * 4 + 2] * hv.z + w3r[k4 * 4 + 3] * hv.w;
            }
            float dz = d0 + d1;
            dz += __shfl_xor(dz, 1, 64);
            dz += __shfl_xor(dz, 2, 64);
            dz += __shfl_xor(dz, 4, 64);
            if (o == 0) xs[cz] = xs[cz] + hdt * (dz + b3c);
            __syncthreads();
        }
        // record states at grid index m = t+1
        const int m = t + 1;
        while (lp < 128 && sidx_sh[lp] == m) {
            if (tid < 128) outb[2 + (size_t)lp * 128 + tid] = xs[tid];
            ++lp;
        }
    }
    // epilogue: scores (final z in xs)
    if (tid < 128) {
        int lane = tid & 63;
        const int item = (tid < 64) ? pos[batch] : neg[batch];
        const float* ev = emb + (size_t)item * 128;
        float sacc = xs[lane] * ev[lane] + xs[lane + 64] * ev[lane + 64];
        #pragma unroll
        for (int s = 1; s < 64; s <<= 1) sacc += __shfl_xor(sacc, s, 64);
        if (lane == 0) outb[(tid < 64) ? 0 : 1] = sacc;
    }
}

extern "C" void kernel_launch(void* const* d_in, const int* in_sizes, int n_in,
                              void* d_out, int out_size, void* d_ws, size_t ws_size,
                              hipStream_t stream) {
    const float* emb   = (const float*)d_in[0];
    const float* w1    = (const float*)d_in[1];
    const float* b1    = (const float*)d_in[2];
    const float* w2    = (const float*)d_in[3];
    const float* b2    = (const float*)d_in[4];
    const float* usert = (const float*)d_in[5];
    const float* vw1   = (const float*)d_in[6];
    const float* vb1   = (const float*)d_in[7];
    const float* vw2   = (const float*)d_in[8];
    const float* vb2   = (const float*)d_in[9];
    const float* vw3   = (const float*)d_in[10];
    const float* vb3   = (const float*)d_in[11];
    const int*   u     = (const int*)d_in[12];
    const int*   hi    = (const int*)d_in[13];
    const float* ht    = (const float*)d_in[14];
    const int*   hl    = (const int*)d_in[15];
    const int*   pos   = (const int*)d_in[16];
    const int*   neg   = (const int*)d_in[17];
    const float* pt    = (const float*)d_in[18];

    int D = in_sizes[2];         // 128
    int B = in_sizes[12];        // 4
    int L = in_sizes[13] / B;    // 128

    // workspace carve-up (no exchange buffers, no memset needed anymore)
    float* jsdv     = (float*)d_ws;                         // B*L
    float* enc      = jsdv + (size_t)B * L;                 // B*L*D
    float* envsb    = enc + (size_t)B * L * D;              // B*MAX_SEG*D
    float* dt_sched = envsb + (size_t)B * MAX_SEG * D;      // B*MAX_T
    int*   envid    = (int*)(dt_sched + (size_t)B * MAX_T); // B*MAX_T
    int*   stateidx = envid + (size_t)B * MAX_T;            // B*L
    int*   Tcnt     = stateidx + (size_t)B * L;             // B

    encode_kernel<<<B * L, D, 0, stream>>>(emb, hi, w1, b1, w2, b2, enc, (float*)d_out, B, L, D);
    jsd_kernel<<<B * 128, 64, 0, stream>>>(enc, hl, jsdv, L, D);
    plan_kernel<<<B, 64, 0, stream>>>(enc, ht, hl, pt, jsdv, envsb, dt_sched, envid, stateidx, Tcnt, B, L, D);
    ode_solo<<<B, 1024, 0, stream>>>(usert, u, vw1, vb1, vw2, vb2, vw3, vb3, emb, pos, neg,
                                     envsb, dt_sched, envid, stateidx, Tcnt,
                                     (float*)d_out, B);
}

// Round 7
// 2017.406 us; speedup vs baseline: 3.3979x; 3.3979x over previous
//
#include <hip/hip_runtime.h>
#include <math.h>

#define W_WIN 5
#define NSUB 2
#define MAX_SEG 64
#define MAX_T 256
#define NWGB 8          // workgroups per batch (ODE)

__device__ __forceinline__ float softplusf(float v) {
    // jax.nn.softplus == logaddexp(v, 0) == max(v,0) + log1p(exp(-|v|))
    return fmaxf(v, 0.0f) + log1pf(expf(-fabsf(v)));
}

// ---------------- wave-level numpy-faithful reductions ----------------
__device__ __forceinline__ float npsum128(float e0, float e1) {
    int lane = threadIdx.x & 63;
    int k = lane & 7;
    float r = __shfl(e0, k, 64);
    #pragma unroll
    for (int m = 1; m < 8; ++m) r += __shfl(e0, k + 8 * m, 64);
    #pragma unroll
    for (int m = 0; m < 8; ++m) r += __shfl(e1, k + 8 * m, 64);
    float r0 = __shfl(r, 0, 64), r1 = __shfl(r, 1, 64), r2 = __shfl(r, 2, 64), r3 = __shfl(r, 3, 64);
    float r4 = __shfl(r, 4, 64), r5 = __shfl(r, 5, 64), r6 = __shfl(r, 6, 64), r7 = __shfl(r, 7, 64);
    return ((r0 + r1) + (r2 + r3)) + ((r4 + r5) + (r6 + r7));
}

__device__ __forceinline__ float wmax128(float e0, float e1) {
    float m = fmaxf(e0, e1);
    #pragma unroll
    for (int s = 1; s < 64; s <<= 1) m = fmaxf(m, __shfl_xor(m, s, 64));
    return m;
}

// ---------------- kernel 1: encoder (also writes traj_t output block) ----------------
__global__ void encode_kernel(const float* __restrict__ emb, const int* __restrict__ hi,
                              const float* __restrict__ w1, const float* __restrict__ b1,
                              const float* __restrict__ w2, const float* __restrict__ b2,
                              float* __restrict__ enc, float* __restrict__ out,
                              int B, int L, int D) {
    __shared__ float x[128];
    __shared__ float h[128];
    int row = blockIdx.x;           // 0 .. B*L-1
    int j = threadIdx.x;            // 0 .. D-1
    int idx = hi[row];
    x[j] = emb[(size_t)idx * D + j];
    __syncthreads();
    float s = b1[j];
    #pragma unroll 8
    for (int i = 0; i < 128; ++i) s += x[i] * w1[i * 128 + j];
    h[j] = fmaxf(s, 0.0f);
    __syncthreads();
    float o = b2[j];
    #pragma unroll 8
    for (int i = 0; i < 128; ++i) o += h[i] * w2[i * 128 + j];
    enc[(size_t)row * D + j] = o;
    int b = row / L, l = row % L;
    size_t OS = 2 + 2 * (size_t)L * D;
    out[(size_t)b * OS + 2 + (size_t)L * D + (size_t)l * D + j] = o;
}

// ---------------- kernel 1b: all window JSDs in parallel (1 wave / position) ----------------
__global__ __launch_bounds__(64) void jsd_kernel(
        const float* __restrict__ enc_all, const int* __restrict__ hl,
        float* __restrict__ jsdv, int L, int D) {
    const int b = blockIdx.x >> 7;
    const int j = blockIdx.x & 127;
    const int n = hl[b];
    if (n < 2 * W_WIN || j > n - 2 * W_WIN) return;
    const int lane = threadIdx.x;
    const float* r = enc_all + ((size_t)b * L + j) * D;
    float ml0 = ((((r[lane]       + r[128 + lane]) + r[256 + lane]) + r[384 + lane]) + r[512 + lane]) / 5.0f;
    float ml1 = ((((r[64 + lane]  + r[192 + lane]) + r[320 + lane]) + r[448 + lane]) + r[576 + lane]) / 5.0f;
    float mr0 = ((((r[640 + lane] + r[768 + lane]) + r[896 + lane]) + r[1024 + lane]) + r[1152 + lane]) / 5.0f;
    float mr1 = ((((r[704 + lane] + r[832 + lane]) + r[960 + lane]) + r[1088 + lane]) + r[1216 + lane]) / 5.0f;
    float mxl = wmax128(ml0, ml1), mxr = wmax128(mr0, mr1);
    float a0 = expf(ml0 - mxl), a1 = expf(ml1 - mxl);
    float c0 = expf(mr0 - mxr), c1 = expf(mr1 - mxr);
    float sl = npsum128(a0, a1), sr = npsum128(c0, c1);
    float p0 = a0 / sl + 1e-8f, p1 = a1 / sl + 1e-8f;
    float q0 = c0 / sr + 1e-8f, q1 = c1 / sr + 1e-8f;
    float sp = npsum128(p0, p1), sq = npsum128(q0, q1);
    p0 /= sp; p1 /= sp; q0 /= sq; q1 /= sq;
    float mv0 = 0.5f * (p0 + q0), mv1 = 0.5f * (p1 + q1);
    float t10 = p0 * logf(p0 / mv0), t11 = p1 * logf(p1 / mv1);
    float t20 = q0 * logf(q0 / mv0), t21 = q1 * logf(q1 / mv1);
    float s1 = npsum128(t10, t11), s2 = npsum128(t20, t21);
    if (lane == 0) jsdv[b * L + j] = 0.5f * s1 + 0.5f * s2;
}

// ---------------- kernel 2: plan building from precomputed JSDs (1 wave / batch) ----------------
__global__ __launch_bounds__(64) void plan_kernel(
        const float* __restrict__ enc_all, const float* __restrict__ ht,
        const int* __restrict__ hl, const float* __restrict__ pt,
        const float* __restrict__ jsdv,
        float* __restrict__ envs, float* __restrict__ dt_sched,
        int* __restrict__ envid, int* __restrict__ stateidx,
        int* __restrict__ Tcnt, int B, int L, int D) {
    const int b = blockIdx.x;
    const int lane = threadIdx.x;   // 0..63
    const float* encg = enc_all + (size_t)b * L * D;
    const float* times = ht + (size_t)b * L;

    __shared__ float encs[128 * 128];
    __shared__ double cand[160];
    __shared__ double bounds[40];
    __shared__ int starts[40];
    __shared__ int seg_s[40], seg_e[40];
    __shared__ int m_sh;

    for (int v = lane; v < 128 * 128 / 4; v += 64)
        ((float4*)encs)[v] = ((const float4*)encg)[v];
    int n = hl[b];
    __syncthreads();

    int nb = 1, ns = 1;             // uniform across the wave
    if (lane == 0) { bounds[0] = (double)times[0]; starts[0] = 0; }
    __syncthreads();

    if (n >= 2 * W_WIN) {
        int j = 0;
        while (j <= n - 2 * W_WIN) {
            float jsd = jsdv[b * L + j];        // uniform broadcast load
            if (jsd > 0.5f) {
                if (nb < 39 && ns < 39) {
                    if (lane == 0) {
                        bounds[nb] = ((double)times[j + W_WIN - 1] + (double)times[j + W_WIN]) * 0.5;
                        starts[ns] = j + W_WIN;
                    }
                    nb++; ns++;
                }
                j += W_WIN;
            } else {
                j += 1;
            }
        }
    }
    __syncthreads();

    {
        double lastb = bounds[nb - 1];
        if ((double)times[n - 1] > lastb) {
            if (lane == 0) bounds[nb] = (double)times[n - 1];
            nb++;
        }
    }
    if (lane == 0) {
        for (int si = 0; si < ns; ++si) {
            seg_s[si] = starts[si];
            seg_e[si] = (si + 1 < ns) ? (starts[si + 1] - 1) : (n - 1);
        }
    }
    __syncthreads();

    int C = 0;
    for (int si = 0; si < ns; ++si) {
        int s = seg_s[si], e = seg_e[si];
        if (lane == 0) {
            double t0 = bounds[si];
            double t1 = (si + 1 < nb) ? bounds[si + 1] : bounds[nb - 1];
            int m = 0;
            cand[m++] = t0;
            for (int l = s; l <= e; ++l) {
                double tv = (double)times[l];
                if (tv < t0 || tv > t1) continue;
                if (tv != cand[m - 1]) cand[m++] = tv;
            }
            if (t1 > cand[m - 1]) cand[m++] = t1;
            for (int k = 1; k < m; ++k)
                if (cand[k] - cand[k - 1] < 1e-6) cand[k] = cand[k - 1] + 1e-6;
            m_sh = m;
        }
        __syncthreads();
        int m = m_sh;
        int K = m - 1;
        if (C + K > MAX_T) K = MAX_T - C;
        for (int k = lane; k < K; k += 64) {
            dt_sched[b * MAX_T + C + k] = (float)(cand[k + 1] - cand[k]);
            envid[b * MAX_T + C + k] = si;
        }
        for (int l = s + lane; l <= e; l += 64) {
            double tv = (double)times[l];
            int best = 0;
            double bd = fabs(cand[0] - tv);
            for (int k = 1; k < m; ++k) {
                double dk = fabs(cand[k] - tv);
                if (dk < bd) { bd = dk; best = k; }
            }
            stateidx[b * L + l] = C + best;
        }
        __syncthreads();
        C += K;
    }

    if (lane == 0) {
        double ptv = (double)pt[b];
        if (ptv > bounds[nb - 1] + 1e-6 && C < MAX_T) {
            double a0d = bounds[nb - 1], a1d = ptv;
            if (a1d - a0d < 1e-6) a1d = a0d + 1e-6;
            dt_sched[b * MAX_T + C] = (float)(a1d - a0d);
            envid[b * MAX_T + C] = ns - 1;
            C++;
        }
        Tcnt[b] = C;
    }
    for (int si = 0; si < ns; ++si) {
        int s = seg_s[si], e = seg_e[si];
        float s0 = 0.0f, s1 = 0.0f;
        for (int l = s; l <= e; ++l) {
            s0 += encs[l * 128 + lane];
            s1 += encs[l * 128 + lane + 64];
        }
        float inv = 1.0f / (float)(e - s + 1);
        envs[((size_t)b * MAX_SEG + si) * 128 + lane] = s0 * inv;
        envs[((size_t)b * MAX_SEG + si) * 128 + lane + 64] = s1 * inv;
    }
}

// ---------------- stamped-word dataflow helpers ----------------
// 8-byte atomic {value, phase}: stamp travels WITH the data — one load both
// detects readiness and delivers the value. Agent-scope (memory-side
// coherence point) only. With a SINGLE rendezvous per substep the slots are
// DOUBLE-BUFFERED by phase parity: slot(parity P) written at phase p is next
// written at p+2, and publish(p+2) <- h1(p+2) <- z(p+1) <- consumed-all
// zp(p+1) <- every WG published p+1 <- every WG consumed p. So no consumer
// can still be polling a slot when it is overwritten. (Protocol proven in
// R5 — passed with baseline-identical absmax; R5's slowdown was spill +
// LDS bank conflicts, both fixed this round.)
typedef unsigned long long u64;

__device__ __forceinline__ void publish(u64* slot, float v, int phase) {
    u64 pk = ((u64)(unsigned)phase << 32) | (u64)__float_as_uint(v);
    __hip_atomic_store(slot, pk, __ATOMIC_RELAXED, __HIP_MEMORY_SCOPE_AGENT);
}
__device__ __forceinline__ u64 ld_agent(const u64* p) {
    return __hip_atomic_load(p, __ATOMIC_RELAXED, __HIP_MEMORY_SCOPE_AGENT);
}
__device__ __forceinline__ void ld8_agent(const u64* b, u64* p) {
    #pragma unroll
    for (int i = 0; i < 8; ++i) p[i] = ld_agent(b + i * 128);
}
__device__ __forceinline__ bool all8p(const u64* p, int phase) {
    bool ok = true;
    #pragma unroll
    for (int i = 0; i < 8; ++i) ok &= ((int)(p[i] >> 32) == phase);
    return ok;
}
__device__ __forceinline__ float fold8(const u64* p) {  // serial g2=0..7 fold
    float s = 0.0f;
    #pragma unroll
    for (int i = 0; i < 8; ++i) s += __uint_as_float((unsigned)p[i]);
    return s;
}

// ---------------- kernel 3: per-batch cooperative ODE, ONE edge/substep ----------------
// grid = 8*NWGB blocks x 512 thr. batch = blockIdx%8, g = blockIdx/8.
//
// R5's one-edge design with its two measured bugs fixed:
//  * SPILL (R5: VGPR capped 128, w1z spilled, WRITE 12.6->25.9MB):
//    amdgpu_waves_per_eu(2,2) pins 2 waves/EU -> 256-VGPR budget for the
//    8-wave block. Register weights = w1z[128] + w2r[64] + w3p[16] = 208.
//    (R6 lesson: RF is 512 VGPR/lane/SIMD -> 256 is the max for 512-thr.)
//  * LDS BANK CONFLICTS (R5: w2t chunk stride ≡ 0 mod 32 banks, 4.3M):
//    W2 returns to REGISTERS in R0's proven skewed q-slice layout; L2 reads
//    h1s with R0's exact pattern (measured 0 conflicts in R0/R2/R3).
//
// Edge A (h1 exchange) stays eliminated: every WG computes ALL 512 h1
// locally (w1z = W1 z-rows for col tid, R0's skewed partial order; the env
// half is segment-constant -> scalar c1nb recomputed from L2 on segment
// change). The ONLY cross-WG exchange is edge B (z-partials, parity
// double-buffered). Associations replicate R0 bitwise (verified in R5).
__global__
__attribute__((amdgpu_flat_work_group_size(512, 512), amdgpu_waves_per_eu(2, 2)))
void ode_coop(
    const float* __restrict__ usert, const int* __restrict__ u,
    const float* __restrict__ vw1, const float* __restrict__ vb1,
    const float* __restrict__ vw2, const float* __restrict__ vb2,
    const float* __restrict__ vw3, const float* __restrict__ vb3,
    const float* __restrict__ emb, const int* __restrict__ pos, const int* __restrict__ neg,
    const float* __restrict__ envs, const float* __restrict__ dtsch,
    const int* __restrict__ envid, const int* __restrict__ stidx,
    const int* __restrict__ Tc,
    u64* zpst,
    float* out, int B)
{
    const int batch = blockIdx.x & 7;
    if (batch >= B) return;
    const int g = blockIdx.x >> 3;      // 0..7
    const int tid = threadIdx.x;        // 0..511

    // L2 mapping: cl = h2 col-in-slice (0..63), q = h1-eighth (0..7)
    const int cl = tid >> 3, q = tid & 7;
    const int c12 = g * 64 + cl;
    // L3-partial mapping: cz = z col (0..127), r = slice-row-quarter (0..3)
    const int cz = tid >> 2, r = tid & 3;

    __shared__ float xs[256];           // [z | env]
    __shared__ float h1s[512];          // FULL h1 (computed locally)
    __shared__ float h2s[64];           // THIS WG's h2 slice only
    __shared__ int sidx_sh[128];
    __shared__ float dts_sh[MAX_T];
    __shared__ int sid_sh[MAX_T];

    // ---- one-time weight staging into registers ----
    // w1z: W1 z-rows for h1 col tid, in R0's skewed partial order:
    // w1z[q2*32 + k4*4 + m] = W1[q2*32 + ((k4+q2)&7)*4 + m][tid]
    float w1z[128];
    #pragma unroll
    for (int q2 = 0; q2 < 4; ++q2) {
        #pragma unroll
        for (int k4 = 0; k4 < 8; ++k4) {
            int roff = q2 * 32 + ((k4 + q2) & 7) * 4;
            #pragma unroll
            for (int m = 0; m < 4; ++m)
                w1z[q2 * 32 + k4 * 4 + m] = vw1[(size_t)(roff + m) * 512 + tid];
        }
    }
    // w2r: R0's skewed q-slice for own output column c12
    float w2r[64];
    #pragma unroll
    for (int k4 = 0; k4 < 16; ++k4) {
        int jj = ((k4 + 2 * q) & 15) * 4;
        #pragma unroll
        for (int m = 0; m < 4; ++m)
            w2r[k4 * 4 + m] = vw2[(size_t)(q * 64 + jj + m) * 512 + c12];
    }
    float w3p[16];
    #pragma unroll
    for (int k = 0; k < 16; ++k)
        w3p[k] = vw3[(size_t)(g * 64 + r * 16 + k) * 128 + cz];

    const float bias1v = vb1[tid];      // h1 col tid (local-L1)
    const float bias2  = vb2[c12];
    const float b3c = (tid < 128) ? vb3[tid] : 0.0f;

    if (tid < 128) sidx_sh[tid] = stidx[batch * 128 + tid];
    if (tid < MAX_T) {
        dts_sh[tid] = dtsch[batch * MAX_T + tid];
        sid_sh[tid] = envid[batch * MAX_T + tid];
    }

    const int T = Tc[batch];
    u64* zpb = zpst + (size_t)batch * 2048;     // 2 parities x 8 WGs x 128 words
    const size_t OS = 2 + 2 * (size_t)128 * 128;
    float* outb = out + (size_t)batch * OS;

    // init z into LDS (every WG loads it directly — no exchange)
    if (tid < 128) xs[tid] = usert[(size_t)u[batch] * 128 + tid];
    __syncthreads();

    // m=0 records (g==0 writes full rows)
    int lp = 0;
    if (g == 0) {
        while (lp < 128 && sidx_sh[lp] == 0) {
            if (tid < 128) outb[2 + (size_t)lp * 128 + tid] = xs[tid];
            ++lp;
        }
    }

    float c1nb = 0.0f;                  // env-half of layer-1 pre-activation
    int prev_si = -1;
    int phase = 0;
    for (int t = 0; t < T; ++t) {
        const int si = sid_sh[t];
        const float hdt = dts_sh[t] * 0.5f;                 // dt / NSUB
        if (si != prev_si) {
            prev_si = si;
            const float* envp = envs + ((size_t)batch * MAX_SEG + si) * 128;
            if (tid >= 128 && tid < 256) xs[tid] = envp[tid - 128];
            __syncthreads();
            // c1nb = (p4+p5)+(p6+p7): R0's env partials, identical skew
            float p4 = 0.0f, p5 = 0.0f, p6 = 0.0f, p7 = 0.0f;
            #pragma unroll
            for (int k4 = 0; k4 < 8; ++k4) {
                {
                    int roff = 4 * 32 + ((k4 + 4) & 7) * 4;
                    float4 xv = *(const float4*)(xs + roff);
                    p4 += vw1[(size_t)(roff + 0) * 512 + tid] * xv.x
                        + vw1[(size_t)(roff + 1) * 512 + tid] * xv.y
                        + vw1[(size_t)(roff + 2) * 512 + tid] * xv.z
                        + vw1[(size_t)(roff + 3) * 512 + tid] * xv.w;
                }
                {
                    int roff = 5 * 32 + ((k4 + 5) & 7) * 4;
                    float4 xv = *(const float4*)(xs + roff);
                    p5 += vw1[(size_t)(roff + 0) * 512 + tid] * xv.x
                        + vw1[(size_t)(roff + 1) * 512 + tid] * xv.y
                        + vw1[(size_t)(roff + 2) * 512 + tid] * xv.z
                        + vw1[(size_t)(roff + 3) * 512 + tid] * xv.w;
                }
                {
                    int roff = 6 * 32 + ((k4 + 6) & 7) * 4;
                    float4 xv = *(const float4*)(xs + roff);
                    p6 += vw1[(size_t)(roff + 0) * 512 + tid] * xv.x
                        + vw1[(size_t)(roff + 1) * 512 + tid] * xv.y
                        + vw1[(size_t)(roff + 2) * 512 + tid] * xv.z
                        + vw1[(size_t)(roff + 3) * 512 + tid] * xv.w;
                }
                {
                    int roff = 7 * 32 + ((k4 + 7) & 7) * 4;
                    float4 xv = *(const float4*)(xs + roff);
                    p7 += vw1[(size_t)(roff + 0) * 512 + tid] * xv.x
                        + vw1[(size_t)(roff + 1) * 512 + tid] * xv.y
                        + vw1[(size_t)(roff + 2) * 512 + tid] * xv.z
                        + vw1[(size_t)(roff + 3) * 512 + tid] * xv.w;
                }
            }
            c1nb = (p4 + p5) + (p6 + p7);
            __syncthreads();
        }
        #pragma unroll
        for (int sub = 0; sub < NSUB; ++sub) {
            ++phase;
            // ---- layer 1 LOCAL: full h1, R0's partial structure replicated ----
            {
                float p0 = 0.0f, p1 = 0.0f, p2 = 0.0f, p3 = 0.0f;
                #pragma unroll
                for (int k4 = 0; k4 < 8; ++k4) {
                    {
                        float4 xv = *(const float4*)(xs + (((k4 + 0) & 7) * 4));
                        p0 += w1z[k4 * 4 + 0] * xv.x + w1z[k4 * 4 + 1] * xv.y
                            + w1z[k4 * 4 + 2] * xv.z + w1z[k4 * 4 + 3] * xv.w;
                    }
                    {
                        float4 xv = *(const float4*)(xs + (32 + ((k4 + 1) & 7) * 4));
                        p1 += w1z[32 + k4 * 4 + 0] * xv.x + w1z[32 + k4 * 4 + 1] * xv.y
                            + w1z[32 + k4 * 4 + 2] * xv.z + w1z[32 + k4 * 4 + 3] * xv.w;
                    }
                    {
                        float4 xv = *(const float4*)(xs + (64 + ((k4 + 2) & 7) * 4));
                        p2 += w1z[64 + k4 * 4 + 0] * xv.x + w1z[64 + k4 * 4 + 1] * xv.y
                            + w1z[64 + k4 * 4 + 2] * xv.z + w1z[64 + k4 * 4 + 3] * xv.w;
                    }
                    {
                        float4 xv = *(const float4*)(xs + (96 + ((k4 + 3) & 7) * 4));
                        p3 += w1z[96 + k4 * 4 + 0] * xv.x + w1z[96 + k4 * 4 + 1] * xv.y
                            + w1z[96 + k4 * 4 + 2] * xv.z + w1z[96 + k4 * 4 + 3] * xv.w;
                    }
                }
                float zt = (p0 + p1) + (p2 + p3);
                h1s[tid] = softplusf((zt + c1nb) + bias1v);
            }
            __syncthreads();
            // ---- layer 2: 512 -> 64 slice, W2 regs (R0 layout), R0 h1s reads ----
            float acc2 = 0.0f;
            #pragma unroll
            for (int k4 = 0; k4 < 16; ++k4) {
                int off = q * 64 + ((k4 + 2 * q) & 15) * 4;
                float4 xv = *(const float4*)(h1s + off);
                acc2 += w2r[k4 * 4 + 0] * xv.x + w2r[k4 * 4 + 1] * xv.y
                      + w2r[k4 * 4 + 2] * xv.z + w2r[k4 * 4 + 3] * xv.w;
            }
            #pragma unroll
            for (int s = 1; s < 8; s <<= 1) acc2 += __shfl_xor(acc2, s, 64);
            if (q == 0) h2s[cl] = softplusf(acc2 + bias2);
            __syncthreads();
            // ---- layer 3 PARTIAL: this WG's 64 h2 rows -> full 128-wide partial ----
            float az = 0.0f;
            #pragma unroll
            for (int k4 = 0; k4 < 4; ++k4) {
                float4 hv = *(const float4*)(h2s + r * 16 + k4 * 4);
                az += w3p[k4 * 4 + 0] * hv.x + w3p[k4 * 4 + 1] * hv.y
                    + w3p[k4 * 4 + 2] * hv.z + w3p[k4 * 4 + 3] * hv.w;
            }
            az += __shfl_xor(az, 1, 64);
            az += __shfl_xor(az, 2, 64);
            // ---- the ONE edge: publish z-partial, poll all 8 (parity buffer) ----
            u64* pb = zpb + (size_t)(phase & 1) * 1024;
            if (r == 0) publish(&pb[g * 128 + cz], az, phase);
            if (tid < 128) {
                u64 s8[8];
                for (;;) {
                    ld8_agent(&pb[tid], s8);
                    if (all8p(s8, phase)) break;
                    __builtin_amdgcn_s_sleep(1);
                }
                float sum = fold8(s8);          // serial g2=0..7 fold (baseline order)
                xs[tid] = xs[tid] + hdt * (sum + b3c);
            }
            __syncthreads();
        }
        // record states at grid index m = t+1 (g==0 writes full rows from xs)
        if (g == 0) {
            const int m = t + 1;
            while (lp < 128 && sidx_sh[lp] == m) {
                if (tid < 128) outb[2 + (size_t)lp * 128 + tid] = xs[tid];
                ++lp;
            }
        }
    }
    // epilogue: scores (g==0; final z in xs)
    if (g == 0 && tid < 128) {
        int lane = tid & 63;
        const int item = (tid < 64) ? pos[batch] : neg[batch];
        const float* ev = emb + (size_t)item * 128;
        float sacc = xs[lane] * ev[lane] + xs[lane + 64] * ev[lane + 64];
        #pragma unroll
        for (int s = 1; s < 64; s <<= 1) sacc += __shfl_xor(sacc, s, 64);
        if (lane == 0) outb[(tid < 64) ? 0 : 1] = sacc;
    }
}

extern "C" void kernel_launch(void* const* d_in, const int* in_sizes, int n_in,
                              void* d_out, int out_size, void* d_ws, size_t ws_size,
                              hipStream_t stream) {
    const float* emb   = (const float*)d_in[0];
    const float* w1    = (const float*)d_in[1];
    const float* b1    = (const float*)d_in[2];
    const float* w2    = (const float*)d_in[3];
    const float* b2    = (const float*)d_in[4];
    const float* usert = (const float*)d_in[5];
    const float* vw1   = (const float*)d_in[6];
    const float* vb1   = (const float*)d_in[7];
    const float* vw2   = (const float*)d_in[8];
    const float* vb2   = (const float*)d_in[9];
    const float* vw3   = (const float*)d_in[10];
    const float* vb3   = (const float*)d_in[11];
    const int*   u     = (const int*)d_in[12];
    const int*   hi    = (const int*)d_in[13];
    const float* ht    = (const float*)d_in[14];
    const int*   hl    = (const int*)d_in[15];
    const int*   pos   = (const int*)d_in[16];
    const int*   neg   = (const int*)d_in[17];
    const float* pt    = (const float*)d_in[18];

    int D = in_sizes[2];         // 128
    int B = in_sizes[12];        // 4
    int L = in_sizes[13] / B;    // 128

    // workspace carve-up: stamped exchange buffer first (8B aligned)
    // zpst: 4 batches x 2 parities x 8 WGs x 128 words
    u64*   zpst     = (u64*)d_ws;
    float* jsdv     = (float*)(zpst + 4 * 2048);            // B*L
    float* enc      = jsdv + (size_t)B * L;                 // B*L*D
    float* envsb    = enc + (size_t)B * L * D;              // B*MAX_SEG*D
    float* dt_sched = envsb + (size_t)B * MAX_SEG * D;      // B*MAX_T
    int*   envid    = (int*)(dt_sched + (size_t)B * MAX_T); // B*MAX_T
    int*   stateidx = envid + (size_t)B * MAX_T;            // B*L
    int*   Tcnt     = stateidx + (size_t)B * L;             // B

    hipMemsetAsync(zpst, 0, 4 * 2048 * sizeof(u64), stream);    // stamps=0 < phase 1
    encode_kernel<<<B * L, D, 0, stream>>>(emb, hi, w1, b1, w2, b2, enc, (float*)d_out, B, L, D);
    jsd_kernel<<<B * 128, 64, 0, stream>>>(enc, hl, jsdv, L, D);
    plan_kernel<<<B, 64, 0, stream>>>(enc, ht, hl, pt, jsdv, envsb, dt_sched, envid, stateidx, Tcnt, B, L, D);
    ode_coop<<<8 * NWGB, 512, 0, stream>>>(usert, u, vw1, vb1, vw2, vb2, vw3, vb3, emb, pos, neg,
                                           envsb, dt_sched, envid, stateidx, Tcnt,
                                           zpst, (float*)d_out, B);
}